// Round 4
// baseline (462.263 us; speedup 1.0000x reference)
//
#include <hip/hip_runtime.h>

#define NN 50000
#define NE 600000
#define F 128

typedef __attribute__((ext_vector_type(4))) float f4;

// ---------------- graph prep ----------------

__global__ void count_deg(const int* __restrict__ dst, int* __restrict__ deg, int E) {
    int e = blockIdx.x * blockDim.x + threadIdx.x;
    if (e < E) atomicAdd(&deg[dst[e]], 1);
}

__global__ __launch_bounds__(1024) void scan_offsets(const int* __restrict__ deg,
                                                     int* __restrict__ off,
                                                     int* __restrict__ cur,
                                                     float* __restrict__ recip, int N) {
    __shared__ int wsum[17];
    int tid = threadIdx.x;
    int wid = tid >> 6;
    int lane = tid & 63;
    int running = 0;
    for (int base = 0; base < N; base += 1024) {
        int idx = base + tid;
        int v = (idx < N) ? deg[idx] : 0;
        int x = v;
        #pragma unroll
        for (int o = 1; o < 64; o <<= 1) {
            int t = __shfl_up(x, o);
            if (lane >= o) x += t;
        }
        if (lane == 63) wsum[wid] = x;
        __syncthreads();
        if (tid == 0) {
            int a = 0;
            #pragma unroll
            for (int w = 0; w < 16; ++w) { int t = wsum[w]; wsum[w] = a; a += t; }
            wsum[16] = a;
        }
        __syncthreads();
        int incl = x + wsum[wid];
        if (idx < N) {
            int start = running + incl - v;
            off[idx] = start;
            cur[idx] = start;
            recip[idx] = 1.0f / (float)max(v, 1);
        }
        running += wsum[16];
        __syncthreads();
    }
}

__global__ void fill_csr(const int* __restrict__ src, const int* __restrict__ dst,
                         int* __restrict__ cur, int* __restrict__ csr, int E) {
    int e = blockIdx.x * blockDim.x + threadIdx.x;
    if (e < E) {
        int pos = atomicAdd(&cur[dst[e]], 1);
        csr[pos] = src[e];
    }
}

// ---------------- mean aggregation (float4 lanes, 2 nodes per wave) ----------------

__global__ __launch_bounds__(256) void agg_mean(const float* __restrict__ x,
                                                const int* __restrict__ off,
                                                const int* __restrict__ deg,
                                                const float* __restrict__ recip,
                                                const int* __restrict__ csr,
                                                float* __restrict__ mean, int N) {
    int node = blockIdx.x * 8 + (threadIdx.x >> 5);
    if (node >= N) return;
    int lane = threadIdx.x & 31;
    int start = off[node];
    int d = deg[node];
    const f4* xp = (const f4*)x;
    f4 a = (f4)0.f;
    int i = 0;
    for (; i + 8 <= d; i += 8) {
        int s[8];
        #pragma unroll
        for (int u = 0; u < 8; ++u) s[u] = csr[start + i + u];
        f4 v[8];
        #pragma unroll
        for (int u = 0; u < 8; ++u) v[u] = xp[(size_t)s[u] * 32 + lane];
        #pragma unroll
        for (int u = 0; u < 8; ++u) a += v[u];
    }
    if (i + 4 <= d) {
        int s[4];
        #pragma unroll
        for (int u = 0; u < 4; ++u) s[u] = csr[start + i + u];
        f4 v[4];
        #pragma unroll
        for (int u = 0; u < 4; ++u) v[u] = xp[(size_t)s[u] * 32 + lane];
        #pragma unroll
        for (int u = 0; u < 4; ++u) a += v[u];
        i += 4;
    }
    for (; i < d; ++i) {
        a += xp[(size_t)csr[start + i] * 32 + lane];
    }
    float r = recip[node];
    ((f4*)mean)[(size_t)node * 32 + lane] = a * r;
}

// ---------------- fused SAGE GEMM: out = act(x@Ws + mean@Wn + b) ----------------
// 32 rows x 128 cols per block (32 KB LDS), 256 threads, each thread 4 rows x
// 4 cols. k-loop in blocks of 4: 8x ds_read_b128 per block (vs 32x b32),
// 1-block-deep W float4 pipeline. In-place safe (x == out).

template <int RELU>
__global__ __launch_bounds__(256) void sage_gemm(const float* __restrict__ x,
                                                 const float* __restrict__ mean,
                                                 const float* __restrict__ Ws,
                                                 const float* __restrict__ Wn,
                                                 const float* __restrict__ bias,
                                                 float* __restrict__ out, int N) {
    __shared__ float sx[32][128];
    __shared__ float sm[32][128];
    int tid = threadIdx.x;
    int r0 = blockIdx.x * 32;

    #pragma unroll
    for (int j = 0; j < 4; ++j) {
        int idx = tid + j * 256;
        int row = idx >> 5;
        int c4 = idx & 31;
        f4 vx = (f4)0.f;
        f4 vm = (f4)0.f;
        if (r0 + row < N) {
            vx = ((const f4*)x)[(size_t)(r0 + row) * 32 + c4];
            vm = ((const f4*)mean)[(size_t)(r0 + row) * 32 + c4];
        }
        *(f4*)&sx[row][c4 * 4] = vx;
        *(f4*)&sm[row][c4 * 4] = vm;
    }
    __syncthreads();

    int cg = (tid & 31) * 4;
    int rg = (tid >> 5) * 4;

    f4 bb = *(const f4*)&bias[cg];
    f4 acc[4];
    #pragma unroll
    for (int i = 0; i < 4; ++i) acc[i] = bb;

    // W pipeline: current block in ws0/wn0, next prefetched into ws1/wn1
    f4 ws0[4], wn0[4];
    #pragma unroll
    for (int u = 0; u < 4; ++u) {
        ws0[u] = *(const f4*)&Ws[u * 128 + cg];
        wn0[u] = *(const f4*)&Wn[u * 128 + cg];
    }

    for (int k0 = 0; k0 < 128; k0 += 4) {
        // LDS reads for this 4-k block: 4 rows x 2 mats, b128 each
        f4 xa[4], ma[4];
        #pragma unroll
        for (int i = 0; i < 4; ++i) {
            xa[i] = *(const f4*)&sx[rg + i][k0];
            ma[i] = *(const f4*)&sm[rg + i][k0];
        }
        // prefetch next W block
        int kp = (k0 + 4 < 128) ? (k0 + 4) : 0;
        f4 ws1[4], wn1[4];
        #pragma unroll
        for (int u = 0; u < 4; ++u) {
            ws1[u] = *(const f4*)&Ws[(kp + u) * 128 + cg];
            wn1[u] = *(const f4*)&Wn[(kp + u) * 128 + cg];
        }
        // 128 FMAs
        #pragma unroll
        for (int u = 0; u < 4; ++u) {
            #pragma unroll
            for (int i = 0; i < 4; ++i) {
                float a = xa[i][u];
                float m = ma[i][u];
                acc[i] += a * ws0[u] + m * wn0[u];
            }
        }
        #pragma unroll
        for (int u = 0; u < 4; ++u) { ws0[u] = ws1[u]; wn0[u] = wn1[u]; }
    }

    #pragma unroll
    for (int i = 0; i < 4; ++i) {
        int row = r0 + rg + i;
        if (row < N) {
            f4 o = acc[i];
            if (RELU) {
                o[0] = fmaxf(o[0], 0.f);
                o[1] = fmaxf(o[1], 0.f);
                o[2] = fmaxf(o[2], 0.f);
                o[3] = fmaxf(o[3], 0.f);
            }
            ((f4*)out)[(size_t)row * 32 + (cg >> 2)] = o;
        }
    }
}

// ---------------- launch ----------------

extern "C" void kernel_launch(void* const* d_in, const int* in_sizes, int n_in,
                              void* d_out, int out_size, void* d_ws, size_t ws_size,
                              hipStream_t stream) {
    const float* feat = (const float*)d_in[0];
    const int* src = (const int*)d_in[1];
    const int* dst = (const int*)d_in[2];
    const float* W1s = (const float*)d_in[3];
    const float* W1n = (const float*)d_in[4];
    const float* b1 = (const float*)d_in[5];
    const float* W2s = (const float*)d_in[6];
    const float* W2n = (const float*)d_in[7];
    const float* b2 = (const float*)d_in[8];
    const float* W3s = (const float*)d_in[9];
    const float* W3n = (const float*)d_in[10];
    const float* b3 = (const float*)d_in[11];
    float* out = (float*)d_out;

    const int N = NN, E = NE;

    char* p = (char*)d_ws;
    auto alloc = [&](size_t bytes) {
        char* q = p;
        p += (bytes + 255) & ~(size_t)255;
        return q;
    };
    int* deg = (int*)alloc((size_t)N * 4);
    int* off = (int*)alloc((size_t)N * 4);
    int* cur = (int*)alloc((size_t)N * 4);
    float* recip = (float*)alloc((size_t)N * 4);
    int* csr = (int*)alloc((size_t)E * 4);
    float* mean = (float*)alloc((size_t)N * F * 4);
    float* h1 = (float*)alloc((size_t)N * F * 4);

    hipMemsetAsync(deg, 0, (size_t)N * 4, stream);
    count_deg<<<(E + 255) / 256, 256, 0, stream>>>(dst, deg, E);
    scan_offsets<<<1, 1024, 0, stream>>>(deg, off, cur, recip, N);
    fill_csr<<<(E + 255) / 256, 256, 0, stream>>>(src, dst, cur, csr, E);

    int aggGrid = (N + 7) / 8;
    int gemmGrid = (N + 31) / 32;

    // layer 1: x = feat -> h1 (relu)
    agg_mean<<<aggGrid, 256, 0, stream>>>(feat, off, deg, recip, csr, mean, N);
    sage_gemm<1><<<gemmGrid, 256, 0, stream>>>(feat, mean, W1s, W1n, b1, h1, N);
    // layer 2: x = h1 -> out (relu)
    agg_mean<<<aggGrid, 256, 0, stream>>>(h1, off, deg, recip, csr, mean, N);
    sage_gemm<1><<<gemmGrid, 256, 0, stream>>>(h1, mean, W2s, W2n, b2, out, N);
    // layer 3: x = out -> out (no relu, in-place safe)
    agg_mean<<<aggGrid, 256, 0, stream>>>(out, off, deg, recip, csr, mean, N);
    sage_gemm<0><<<gemmGrid, 256, 0, stream>>>(out, mean, W3s, W3n, b3, out, N);
}

// Round 5
// 426.672 us; speedup vs baseline: 1.0834x; 1.0834x over previous
//
#include <hip/hip_runtime.h>

#define NN 50000
#define NE 600000
#define F 128

typedef __attribute__((ext_vector_type(4))) float f4;

// ---------------- graph prep ----------------

__global__ void count_deg(const int* __restrict__ dst, int* __restrict__ deg, int E) {
    int e = blockIdx.x * blockDim.x + threadIdx.x;
    if (e < E) atomicAdd(&deg[dst[e]], 1);
}

__global__ __launch_bounds__(1024) void scan_offsets(const int* __restrict__ deg,
                                                     int* __restrict__ off,
                                                     int* __restrict__ cur,
                                                     float* __restrict__ recip, int N) {
    __shared__ int wsum[17];
    int tid = threadIdx.x;
    int wid = tid >> 6;
    int lane = tid & 63;
    int running = 0;
    for (int base = 0; base < N; base += 1024) {
        int idx = base + tid;
        int v = (idx < N) ? deg[idx] : 0;
        int x = v;
        #pragma unroll
        for (int o = 1; o < 64; o <<= 1) {
            int t = __shfl_up(x, o);
            if (lane >= o) x += t;
        }
        if (lane == 63) wsum[wid] = x;
        __syncthreads();
        if (tid == 0) {
            int a = 0;
            #pragma unroll
            for (int w = 0; w < 16; ++w) { int t = wsum[w]; wsum[w] = a; a += t; }
            wsum[16] = a;
        }
        __syncthreads();
        int incl = x + wsum[wid];
        if (idx < N) {
            int start = running + incl - v;
            off[idx] = start;
            cur[idx] = start;
            recip[idx] = 1.0f / (float)max(v, 1);
        }
        running += wsum[16];
        __syncthreads();
    }
}

__global__ void fill_csr(const int* __restrict__ src, const int* __restrict__ dst,
                         int* __restrict__ cur, int* __restrict__ csr, int E) {
    int e = blockIdx.x * blockDim.x + threadIdx.x;
    if (e < E) {
        int pos = atomicAdd(&cur[dst[e]], 1);
        csr[pos] = src[e];
    }
}

// ---------------- mean aggregation ----------------
// float4 lanes, 2 nodes per wave (32 lanes each). Full 8-edge blocks, then
// ONE masked 8-block for the tail (clamped gather index + select) — no
// serial scalar tail, all loads within a round independent.

__global__ __launch_bounds__(256) void agg_mean(const float* __restrict__ x,
                                                const int* __restrict__ off,
                                                const int* __restrict__ deg,
                                                const float* __restrict__ recip,
                                                const int* __restrict__ csr,
                                                float* __restrict__ mean, int N) {
    int node = blockIdx.x * 8 + (threadIdx.x >> 5);
    if (node >= N) return;
    int lane = threadIdx.x & 31;
    int start = off[node];
    int d = deg[node];
    const f4* xp = (const f4*)x;
    f4 a = (f4)0.f;
    int nfull = d & ~7;
    int i = 0;
    for (; i < nfull; i += 8) {
        int s[8];
        #pragma unroll
        for (int u = 0; u < 8; ++u) s[u] = csr[start + i + u];
        f4 v[8];
        #pragma unroll
        for (int u = 0; u < 8; ++u) v[u] = xp[(size_t)s[u] * 32 + lane];
        #pragma unroll
        for (int u = 0; u < 8; ++u) a += v[u];
    }
    if (i < d) {
        int dm1 = d - 1;
        int s[8];
        #pragma unroll
        for (int u = 0; u < 8; ++u) {
            int idx = i + u;
            s[u] = csr[start + ((idx < dm1) ? idx : dm1)];
        }
        f4 v[8];
        #pragma unroll
        for (int u = 0; u < 8; ++u) v[u] = xp[(size_t)s[u] * 32 + lane];
        #pragma unroll
        for (int u = 0; u < 8; ++u) a += (i + u < d) ? v[u] : (f4)0.f;
    }
    float r = recip[node];
    ((f4*)mean)[(size_t)node * 32 + lane] = a * r;
}

// ---------------- fused SAGE GEMM: out = act(x@Ws + mean@Wn + b) ----------------
// 32 rows x 128 cols per block (32 KB LDS), 256 threads, each thread 4 rows x
// 4 cols. k-loop in 8-k iterations of two 4-k phases; W rows double-buffered
// in named A/B register sets (copy-free), LDS read as ds_read_b128, FMAs as
// explicit scalar fmaf chains (2 VALU ops per output component).
// In-place safe (x == out).

template <int RELU>
__global__ __launch_bounds__(256) void sage_gemm(const float* __restrict__ x,
                                                 const float* __restrict__ mean,
                                                 const float* __restrict__ Ws,
                                                 const float* __restrict__ Wn,
                                                 const float* __restrict__ bias,
                                                 float* __restrict__ out, int N) {
    __shared__ float sx[32][128];
    __shared__ float sm[32][128];
    int tid = threadIdx.x;
    int r0 = blockIdx.x * 32;

    #pragma unroll
    for (int j = 0; j < 4; ++j) {
        int idx = tid + j * 256;
        int row = idx >> 5;
        int c4 = idx & 31;
        f4 vx = (f4)0.f;
        f4 vm = (f4)0.f;
        if (r0 + row < N) {
            vx = ((const f4*)x)[(size_t)(r0 + row) * 32 + c4];
            vm = ((const f4*)mean)[(size_t)(r0 + row) * 32 + c4];
        }
        *(f4*)&sx[row][c4 * 4] = vx;
        *(f4*)&sm[row][c4 * 4] = vm;
    }
    __syncthreads();

    int cg = (tid & 31) * 4;
    int rg = (tid >> 5) * 4;

    f4 bb = *(const f4*)&bias[cg];
    float acc[4][4];
    #pragma unroll
    for (int i = 0; i < 4; ++i) {
        acc[i][0] = bb[0]; acc[i][1] = bb[1]; acc[i][2] = bb[2]; acc[i][3] = bb[3];
    }

    f4 wsA[4], wnA[4], wsB[4], wnB[4];
    #pragma unroll
    for (int u = 0; u < 4; ++u) {
        wsA[u] = *(const f4*)&Ws[u * 128 + cg];
        wnA[u] = *(const f4*)&Wn[u * 128 + cg];
    }

    for (int k0 = 0; k0 < 128; k0 += 8) {
        // prefetch rows k0+4..k0+7 into B
        #pragma unroll
        for (int u = 0; u < 4; ++u) {
            wsB[u] = *(const f4*)&Ws[(k0 + 4 + u) * 128 + cg];
            wnB[u] = *(const f4*)&Wn[(k0 + 4 + u) * 128 + cg];
        }
        // phase A: k0..k0+3
        {
            f4 xa[4], ma[4];
            #pragma unroll
            for (int i = 0; i < 4; ++i) {
                xa[i] = *(const f4*)&sx[rg + i][k0];
                ma[i] = *(const f4*)&sm[rg + i][k0];
            }
            #pragma unroll
            for (int u = 0; u < 4; ++u) {
                #pragma unroll
                for (int i = 0; i < 4; ++i) {
                    float a = xa[i][u];
                    float m = ma[i][u];
                    acc[i][0] = fmaf(a, wsA[u][0], fmaf(m, wnA[u][0], acc[i][0]));
                    acc[i][1] = fmaf(a, wsA[u][1], fmaf(m, wnA[u][1], acc[i][1]));
                    acc[i][2] = fmaf(a, wsA[u][2], fmaf(m, wnA[u][2], acc[i][2]));
                    acc[i][3] = fmaf(a, wsA[u][3], fmaf(m, wnA[u][3], acc[i][3]));
                }
            }
        }
        // prefetch rows k0+8..k0+11 into A (wraps to row 0 on last iter; unused)
        int ka = (k0 + 8) & 127;
        #pragma unroll
        for (int u = 0; u < 4; ++u) {
            wsA[u] = *(const f4*)&Ws[(ka + u) * 128 + cg];
            wnA[u] = *(const f4*)&Wn[(ka + u) * 128 + cg];
        }
        // phase B: k0+4..k0+7
        {
            f4 xa[4], ma[4];
            #pragma unroll
            for (int i = 0; i < 4; ++i) {
                xa[i] = *(const f4*)&sx[rg + i][k0 + 4];
                ma[i] = *(const f4*)&sm[rg + i][k0 + 4];
            }
            #pragma unroll
            for (int u = 0; u < 4; ++u) {
                #pragma unroll
                for (int i = 0; i < 4; ++i) {
                    float a = xa[i][u];
                    float m = ma[i][u];
                    acc[i][0] = fmaf(a, wsB[u][0], fmaf(m, wnB[u][0], acc[i][0]));
                    acc[i][1] = fmaf(a, wsB[u][1], fmaf(m, wnB[u][1], acc[i][1]));
                    acc[i][2] = fmaf(a, wsB[u][2], fmaf(m, wnB[u][2], acc[i][2]));
                    acc[i][3] = fmaf(a, wsB[u][3], fmaf(m, wnB[u][3], acc[i][3]));
                }
            }
        }
    }

    #pragma unroll
    for (int i = 0; i < 4; ++i) {
        int row = r0 + rg + i;
        if (row < N) {
            f4 o;
            o[0] = acc[i][0]; o[1] = acc[i][1]; o[2] = acc[i][2]; o[3] = acc[i][3];
            if (RELU) {
                o[0] = fmaxf(o[0], 0.f);
                o[1] = fmaxf(o[1], 0.f);
                o[2] = fmaxf(o[2], 0.f);
                o[3] = fmaxf(o[3], 0.f);
            }
            ((f4*)out)[(size_t)row * 32 + (cg >> 2)] = o;
        }
    }
}

// ---------------- launch ----------------

extern "C" void kernel_launch(void* const* d_in, const int* in_sizes, int n_in,
                              void* d_out, int out_size, void* d_ws, size_t ws_size,
                              hipStream_t stream) {
    const float* feat = (const float*)d_in[0];
    const int* src = (const int*)d_in[1];
    const int* dst = (const int*)d_in[2];
    const float* W1s = (const float*)d_in[3];
    const float* W1n = (const float*)d_in[4];
    const float* b1 = (const float*)d_in[5];
    const float* W2s = (const float*)d_in[6];
    const float* W2n = (const float*)d_in[7];
    const float* b2 = (const float*)d_in[8];
    const float* W3s = (const float*)d_in[9];
    const float* W3n = (const float*)d_in[10];
    const float* b3 = (const float*)d_in[11];
    float* out = (float*)d_out;

    const int N = NN, E = NE;

    char* p = (char*)d_ws;
    auto alloc = [&](size_t bytes) {
        char* q = p;
        p += (bytes + 255) & ~(size_t)255;
        return q;
    };
    int* deg = (int*)alloc((size_t)N * 4);
    int* off = (int*)alloc((size_t)N * 4);
    int* cur = (int*)alloc((size_t)N * 4);
    float* recip = (float*)alloc((size_t)N * 4);
    int* csr = (int*)alloc((size_t)E * 4);
    float* mean = (float*)alloc((size_t)N * F * 4);
    float* h1 = (float*)alloc((size_t)N * F * 4);

    hipMemsetAsync(deg, 0, (size_t)N * 4, stream);
    count_deg<<<(E + 255) / 256, 256, 0, stream>>>(dst, deg, E);
    scan_offsets<<<1, 1024, 0, stream>>>(deg, off, cur, recip, N);
    fill_csr<<<(E + 255) / 256, 256, 0, stream>>>(src, dst, cur, csr, E);

    int aggGrid = (N + 7) / 8;
    int gemmGrid = (N + 31) / 32;

    // layer 1: x = feat -> h1 (relu)
    agg_mean<<<aggGrid, 256, 0, stream>>>(feat, off, deg, recip, csr, mean, N);
    sage_gemm<1><<<gemmGrid, 256, 0, stream>>>(feat, mean, W1s, W1n, b1, h1, N);
    // layer 2: x = h1 -> out (relu)
    agg_mean<<<aggGrid, 256, 0, stream>>>(h1, off, deg, recip, csr, mean, N);
    sage_gemm<1><<<gemmGrid, 256, 0, stream>>>(h1, mean, W2s, W2n, b2, out, N);
    // layer 3: x = out -> out (no relu, in-place safe)
    agg_mean<<<aggGrid, 256, 0, stream>>>(out, off, deg, recip, csr, mean, N);
    sage_gemm<0><<<gemmGrid, 256, 0, stream>>>(out, mean, W3s, W3n, b3, out, N);
}

// Round 6
// 360.785 us; speedup vs baseline: 1.2813x; 1.1826x over previous
//
#include <hip/hip_runtime.h>

#define NN 50000
#define NE 600000
#define F 128

typedef __attribute__((ext_vector_type(4))) float f4;
typedef __attribute__((ext_vector_type(4))) float f32x4;
typedef __bf16 bf16x8 __attribute__((ext_vector_type(8)));
typedef short short8v __attribute__((ext_vector_type(8)));

__device__ inline ushort f2bf(float f) {
    uint u = __builtin_bit_cast(uint, f);
    uint r = (u + 0x7FFFu + ((u >> 16) & 1u)) >> 16;
    return (ushort)r;
}

// ---------------- graph prep ----------------

__global__ void count_deg(const int* __restrict__ dst, int* __restrict__ deg, int E) {
    int e = blockIdx.x * blockDim.x + threadIdx.x;
    if (e < E) atomicAdd(&deg[dst[e]], 1);
}

__global__ __launch_bounds__(1024) void scan_offsets(const int* __restrict__ deg,
                                                     int* __restrict__ off,
                                                     int* __restrict__ cur,
                                                     float* __restrict__ recip, int N) {
    __shared__ int wsum[17];
    int tid = threadIdx.x;
    int wid = tid >> 6;
    int lane = tid & 63;
    int running = 0;
    for (int base = 0; base < N; base += 1024) {
        int idx = base + tid;
        int v = (idx < N) ? deg[idx] : 0;
        int x = v;
        #pragma unroll
        for (int o = 1; o < 64; o <<= 1) {
            int t = __shfl_up(x, o);
            if (lane >= o) x += t;
        }
        if (lane == 63) wsum[wid] = x;
        __syncthreads();
        if (tid == 0) {
            int a = 0;
            #pragma unroll
            for (int w = 0; w < 16; ++w) { int t = wsum[w]; wsum[w] = a; a += t; }
            wsum[16] = a;
        }
        __syncthreads();
        int incl = x + wsum[wid];
        if (idx < N) {
            int start = running + incl - v;
            off[idx] = start;
            cur[idx] = start;
            recip[idx] = 1.0f / (float)max(v, 1);
        }
        running += wsum[16];
        __syncthreads();
    }
}

__global__ void fill_csr(const int* __restrict__ src, const int* __restrict__ dst,
                         int* __restrict__ cur, int* __restrict__ csr, int E) {
    int e = blockIdx.x * blockDim.x + threadIdx.x;
    if (e < E) {
        int pos = atomicAdd(&cur[dst[e]], 1);
        csr[pos] = src[e];
    }
}

// ---------------- weight prep: Bt[col][k] bf16, k<128 from Ws, k>=128 from Wn ----------------

__global__ __launch_bounds__(256) void wt_prep(const float* __restrict__ Ws,
                                               const float* __restrict__ Wn,
                                               ushort* __restrict__ Bt) {
    int col = blockIdx.x;
    int k = threadIdx.x;
    float v = (k < 128) ? Ws[k * 128 + col] : Wn[(k - 128) * 128 + col];
    Bt[col * 256 + k] = f2bf(v);
}

// ---------------- mean aggregation (f32, unchanged) ----------------

__global__ __launch_bounds__(256) void agg_mean(const float* __restrict__ x,
                                                const int* __restrict__ off,
                                                const int* __restrict__ deg,
                                                const float* __restrict__ recip,
                                                const int* __restrict__ csr,
                                                float* __restrict__ mean, int N) {
    int node = blockIdx.x * 8 + (threadIdx.x >> 5);
    if (node >= N) return;
    int lane = threadIdx.x & 31;
    int start = off[node];
    int d = deg[node];
    const f4* xp = (const f4*)x;
    f4 a = (f4)0.f;
    int nfull = d & ~7;
    int i = 0;
    for (; i < nfull; i += 8) {
        int s[8];
        #pragma unroll
        for (int u = 0; u < 8; ++u) s[u] = csr[start + i + u];
        f4 v[8];
        #pragma unroll
        for (int u = 0; u < 8; ++u) v[u] = xp[(size_t)s[u] * 32 + lane];
        #pragma unroll
        for (int u = 0; u < 8; ++u) a += v[u];
    }
    if (i < d) {
        int dm1 = d - 1;
        int s[8];
        #pragma unroll
        for (int u = 0; u < 8; ++u) {
            int idx = i + u;
            s[u] = csr[start + ((idx < dm1) ? idx : dm1)];
        }
        f4 v[8];
        #pragma unroll
        for (int u = 0; u < 8; ++u) v[u] = xp[(size_t)s[u] * 32 + lane];
        #pragma unroll
        for (int u = 0; u < 8; ++u) a += (i + u < d) ? v[u] : (f4)0.f;
    }
    float r = recip[node];
    ((f4*)mean)[(size_t)node * 32 + lane] = a * r;
}

// ---------------- MFMA SAGE GEMM: out = act([x|mean] @ Bt^T + b) ----------------
// 32 rows x 128 cols per block, 256 threads (4 waves). K = 256 (x then mean).
// A staged in LDS as bf16, XOR-swizzled (byte ^= (row&7)<<4). Wave w: rows
// 16*(w&1).., cols 64*(w>>1)..; 4 col-tiles x 8 k-steps of
// mfma_f32_16x16x32_bf16, f32 accumulate. B-frags are 16B contiguous loads
// from pre-transposed Bt[col][k] (L2-resident, 64 KB).
// In-place safe (x == out): block stages its 32 rows before writing them.

template <int RELU>
__global__ __launch_bounds__(256) void sage_gemm(const float* __restrict__ x,
                                                 const float* __restrict__ mean,
                                                 const ushort* __restrict__ Bt,
                                                 const float* __restrict__ bias,
                                                 float* __restrict__ out, int N) {
    __shared__ ushort sa[32 * 256];  // 16 KB, [row][k] bf16, swizzled
    int tid = threadIdx.x;
    int r0 = blockIdx.x * 32;

    // ---- stage A = [x | mean] as bf16 ----
    {
        int row = tid >> 3;      // 0..31
        int kc = tid & 7;        // 32-k chunk
        int grow = r0 + row;
        const float* srcp = (kc < 4) ? &x[(size_t)grow * 128 + kc * 32]
                                     : &mean[(size_t)grow * 128 + (kc - 4) * 32];
        f4 vv[8];
        if (grow < N) {
            const f4* sp = (const f4*)srcp;
            #pragma unroll
            for (int u = 0; u < 8; ++u) vv[u] = sp[u];
        } else {
            #pragma unroll
            for (int u = 0; u < 8; ++u) vv[u] = (f4)0.f;
        }
        ushort tmp[32];
        #pragma unroll
        for (int u = 0; u < 8; ++u) {
            tmp[u * 4 + 0] = f2bf(vv[u][0]);
            tmp[u * 4 + 1] = f2bf(vv[u][1]);
            tmp[u * 4 + 2] = f2bf(vv[u][2]);
            tmp[u * 4 + 3] = f2bf(vv[u][3]);
        }
        uint base = (uint)(row * 512 + kc * 64);
        uint sw = ((uint)row & 7u) << 4;
        #pragma unroll
        for (int c = 0; c < 4; ++c) {
            short8v w;
            #pragma unroll
            for (int j = 0; j < 8; ++j) w[j] = (short)tmp[c * 8 + j];
            *(short8v*)((char*)sa + ((base + c * 16) ^ sw)) = w;
        }
    }
    __syncthreads();

    int lane = tid & 63;
    int wid = tid >> 6;
    int wr = wid & 1;        // row half
    int wc = wid >> 1;       // col quarter (64 cols)
    int l15 = lane & 15;
    int lg = lane >> 4;      // k-group

    // ---- load A fragments (8 k-steps) ----
    int arow = wr * 16 + l15;
    uint abase = (uint)(arow * 512 + lg * 16);
    uint asw = ((uint)arow & 7u) << 4;
    bf16x8 a[8];
    #pragma unroll
    for (int ks = 0; ks < 8; ++ks) {
        a[ks] = *(const bf16x8*)((const char*)sa + ((abase + (uint)ks * 64) ^ asw));
    }

    // ---- MFMA: 4 col-tiles x 8 k-steps ----
    f32x4 acc[4];
    #pragma unroll
    for (int ct = 0; ct < 4; ++ct) acc[ct] = (f32x4)0.f;

    #pragma unroll
    for (int ct = 0; ct < 4; ++ct) {
        int bcol = wc * 64 + ct * 16 + l15;
        const ushort* bp = Bt + bcol * 256 + lg * 8;
        #pragma unroll
        for (int ks = 0; ks < 8; ++ks) {
            bf16x8 b = *(const bf16x8*)(bp + ks * 32);
            acc[ct] = __builtin_amdgcn_mfma_f32_16x16x32_bf16(a[ks], b, acc[ct], 0, 0, 0);
        }
    }

    // ---- epilogue: C/D layout col=lane&15, row=(lane>>4)*4+r ----
    int crow = r0 + wr * 16 + lg * 4;
    #pragma unroll
    for (int ct = 0; ct < 4; ++ct) {
        int col = wc * 64 + ct * 16 + l15;
        float bv = bias[col];
        #pragma unroll
        for (int r = 0; r < 4; ++r) {
            int row = crow + r;
            if (row < N) {
                float v = acc[ct][r] + bv;
                if (RELU) v = fmaxf(v, 0.f);
                out[(size_t)row * 128 + col] = v;
            }
        }
    }
}

// ---------------- launch ----------------

extern "C" void kernel_launch(void* const* d_in, const int* in_sizes, int n_in,
                              void* d_out, int out_size, void* d_ws, size_t ws_size,
                              hipStream_t stream) {
    const float* feat = (const float*)d_in[0];
    const int* src = (const int*)d_in[1];
    const int* dst = (const int*)d_in[2];
    const float* W1s = (const float*)d_in[3];
    const float* W1n = (const float*)d_in[4];
    const float* b1 = (const float*)d_in[5];
    const float* W2s = (const float*)d_in[6];
    const float* W2n = (const float*)d_in[7];
    const float* b2 = (const float*)d_in[8];
    const float* W3s = (const float*)d_in[9];
    const float* W3n = (const float*)d_in[10];
    const float* b3 = (const float*)d_in[11];
    float* out = (float*)d_out;

    const int N = NN, E = NE;

    char* p = (char*)d_ws;
    auto alloc = [&](size_t bytes) {
        char* q = p;
        p += (bytes + 255) & ~(size_t)255;
        return q;
    };
    int* deg = (int*)alloc((size_t)N * 4);
    int* off = (int*)alloc((size_t)N * 4);
    int* cur = (int*)alloc((size_t)N * 4);
    float* recip = (float*)alloc((size_t)N * 4);
    int* csr = (int*)alloc((size_t)E * 4);
    float* mean = (float*)alloc((size_t)N * F * 4);
    float* h1 = (float*)alloc((size_t)N * F * 4);
    ushort* Bt1 = (ushort*)alloc(128 * 256 * 2);
    ushort* Bt2 = (ushort*)alloc(128 * 256 * 2);
    ushort* Bt3 = (ushort*)alloc(128 * 256 * 2);

    // weight prep (independent of graph prep)
    wt_prep<<<128, 256, 0, stream>>>(W1s, W1n, Bt1);
    wt_prep<<<128, 256, 0, stream>>>(W2s, W2n, Bt2);
    wt_prep<<<128, 256, 0, stream>>>(W3s, W3n, Bt3);

    hipMemsetAsync(deg, 0, (size_t)N * 4, stream);
    count_deg<<<(E + 255) / 256, 256, 0, stream>>>(dst, deg, E);
    scan_offsets<<<1, 1024, 0, stream>>>(deg, off, cur, recip, N);
    fill_csr<<<(E + 255) / 256, 256, 0, stream>>>(src, dst, cur, csr, E);

    int aggGrid = (N + 7) / 8;
    int gemmGrid = (N + 31) / 32;

    // layer 1: x = feat -> h1 (relu)
    agg_mean<<<aggGrid, 256, 0, stream>>>(feat, off, deg, recip, csr, mean, N);
    sage_gemm<1><<<gemmGrid, 256, 0, stream>>>(feat, mean, Bt1, b1, h1, N);
    // layer 2: x = h1 -> out (relu)
    agg_mean<<<aggGrid, 256, 0, stream>>>(h1, off, deg, recip, csr, mean, N);
    sage_gemm<1><<<gemmGrid, 256, 0, stream>>>(h1, mean, Bt2, b2, out, N);
    // layer 3: x = out -> out (no relu, in-place safe)
    agg_mean<<<aggGrid, 256, 0, stream>>>(out, off, deg, recip, csr, mean, N);
    sage_gemm<0><<<gemmGrid, 256, 0, stream>>>(out, mean, Bt3, b3, out, N);
}

// Round 7
// 253.412 us; speedup vs baseline: 1.8242x; 1.4237x over previous
//
#include <hip/hip_runtime.h>

#define NN 50000
#define NE 600000
#define F 128

typedef __attribute__((ext_vector_type(4))) float f4;
typedef __attribute__((ext_vector_type(4))) float f32x4;
typedef __bf16 bf16x8 __attribute__((ext_vector_type(8)));
typedef short short8v __attribute__((ext_vector_type(8)));
typedef unsigned short u16x4 __attribute__((ext_vector_type(4)));

__device__ inline ushort f2bf(float f) {
    uint u = __builtin_bit_cast(uint, f);
    uint r = (u + 0x7FFFu + ((u >> 16) & 1u)) >> 16;
    return (ushort)r;
}
__device__ inline float bf2f(ushort u) {
    uint t = ((uint)u) << 16;
    return __builtin_bit_cast(float, t);
}

// ---------------- graph prep ----------------

__global__ void count_deg(const int* __restrict__ dst, int* __restrict__ deg, int E) {
    int e = blockIdx.x * blockDim.x + threadIdx.x;
    if (e < E) atomicAdd(&deg[dst[e]], 1);
}

// pass 1: per-block (1024 elems) sums
__global__ __launch_bounds__(1024) void scan_part1(const int* __restrict__ deg,
                                                   int* __restrict__ bsum, int N) {
    __shared__ int ws[16];
    int tid = threadIdx.x;
    int idx = blockIdx.x * 1024 + tid;
    int v = (idx < N) ? deg[idx] : 0;
    #pragma unroll
    for (int o = 32; o; o >>= 1) v += __shfl_down(v, o);
    if ((tid & 63) == 0) ws[tid >> 6] = v;
    __syncthreads();
    if (tid < 64) {
        int t = (tid < 16) ? ws[tid] : 0;
        #pragma unroll
        for (int o = 8; o; o >>= 1) t += __shfl_down(t, o);
        if (tid == 0) bsum[blockIdx.x] = t;
    }
}

// pass 2: exclusive scan of block sums (nb <= 64), in place
__global__ void scan_part2(int* __restrict__ bsum, int nb) {
    int lane = threadIdx.x;
    int v = (lane < nb) ? bsum[lane] : 0;
    int x = v;
    #pragma unroll
    for (int o = 1; o < 64; o <<= 1) {
        int t = __shfl_up(x, o);
        if (lane >= o) x += t;
    }
    if (lane < nb) bsum[lane] = x - v;
}

// pass 3: local scan + block base -> off/cur/recip
__global__ __launch_bounds__(1024) void scan_part3(const int* __restrict__ deg,
                                                   const int* __restrict__ bsum,
                                                   int* __restrict__ off,
                                                   int* __restrict__ cur,
                                                   float* __restrict__ recip, int N) {
    __shared__ int wsum[16];
    int tid = threadIdx.x;
    int wid = tid >> 6;
    int lane = tid & 63;
    int idx = blockIdx.x * 1024 + tid;
    int v = (idx < N) ? deg[idx] : 0;
    int x = v;
    #pragma unroll
    for (int o = 1; o < 64; o <<= 1) {
        int t = __shfl_up(x, o);
        if (lane >= o) x += t;
    }
    if (lane == 63) wsum[wid] = x;
    __syncthreads();
    if (tid == 0) {
        int a = 0;
        #pragma unroll
        for (int w = 0; w < 16; ++w) { int t = wsum[w]; wsum[w] = a; a += t; }
    }
    __syncthreads();
    int incl = x + wsum[wid];
    if (idx < N) {
        int start = bsum[blockIdx.x] + incl - v;
        off[idx] = start;
        cur[idx] = start;
        recip[idx] = 1.0f / (float)max(v, 1);
    }
}

__global__ void fill_csr(const int* __restrict__ src, const int* __restrict__ dst,
                         int* __restrict__ cur, int* __restrict__ csr, int E) {
    int e = blockIdx.x * blockDim.x + threadIdx.x;
    if (e < E) {
        int pos = atomicAdd(&cur[dst[e]], 1);
        csr[pos] = src[e];
    }
}

// ---------------- weight prep: Bt[col][k] bf16 for all 3 layers ----------------

__global__ __launch_bounds__(256) void wt_prep(const float* __restrict__ W1s, const float* __restrict__ W1n,
                                               const float* __restrict__ W2s, const float* __restrict__ W2n,
                                               const float* __restrict__ W3s, const float* __restrict__ W3n,
                                               ushort* __restrict__ Bt1, ushort* __restrict__ Bt2,
                                               ushort* __restrict__ Bt3) {
    int layer = blockIdx.y;
    const float* Ws = (layer == 0) ? W1s : (layer == 1) ? W2s : W3s;
    const float* Wn = (layer == 0) ? W1n : (layer == 1) ? W2n : W3n;
    ushort* Bt = (layer == 0) ? Bt1 : (layer == 1) ? Bt2 : Bt3;
    int col = blockIdx.x;
    int k = threadIdx.x;
    float v = (k < 128) ? Ws[k * 128 + col] : Wn[(k - 128) * 128 + col];
    Bt[col * 256 + k] = f2bf(v);
}

// ---------------- f32 -> bf16 feature convert ----------------

__global__ __launch_bounds__(256) void to_bf16(const float* __restrict__ in,
                                               ushort* __restrict__ out, int n8) {
    int i = blockIdx.x * 256 + threadIdx.x;
    if (i < n8) {
        const f4* p = (const f4*)in + (size_t)i * 2;
        f4 a = p[0], b = p[1];
        short8v w;
        w[0] = (short)f2bf(a[0]); w[1] = (short)f2bf(a[1]);
        w[2] = (short)f2bf(a[2]); w[3] = (short)f2bf(a[3]);
        w[4] = (short)f2bf(b[0]); w[5] = (short)f2bf(b[1]);
        w[6] = (short)f2bf(b[2]); w[7] = (short)f2bf(b[3]);
        ((short8v*)out)[i] = w;
    }
}

// ---------------- mean aggregation (bf16 gather, f32 accumulate, bf16 out) ----------------
// 2 nodes per wave (32 lanes each, 4 cols/lane). Full 8-edge blocks + one
// masked 8-block tail (all loads in a round independent).

__global__ __launch_bounds__(256) void agg_mean(const ushort* __restrict__ xb,
                                                const int* __restrict__ off,
                                                const int* __restrict__ deg,
                                                const float* __restrict__ recip,
                                                const int* __restrict__ csr,
                                                ushort* __restrict__ meanb, int N) {
    int node = blockIdx.x * 8 + (threadIdx.x >> 5);
    if (node >= N) return;
    int lane = threadIdx.x & 31;
    int start = off[node];
    int d = deg[node];
    const u16x4* xp = (const u16x4*)xb;
    f4 a = (f4)0.f;
    int nfull = d & ~7;
    int i = 0;
    for (; i < nfull; i += 8) {
        int s[8];
        #pragma unroll
        for (int u = 0; u < 8; ++u) s[u] = csr[start + i + u];
        u16x4 v[8];
        #pragma unroll
        for (int u = 0; u < 8; ++u) v[u] = xp[(size_t)s[u] * 32 + lane];
        #pragma unroll
        for (int u = 0; u < 8; ++u) {
            a[0] += bf2f(v[u][0]); a[1] += bf2f(v[u][1]);
            a[2] += bf2f(v[u][2]); a[3] += bf2f(v[u][3]);
        }
    }
    if (i < d) {
        int dm1 = d - 1;
        int s[8];
        #pragma unroll
        for (int u = 0; u < 8; ++u) {
            int idx = i + u;
            s[u] = csr[start + ((idx < dm1) ? idx : dm1)];
        }
        u16x4 v[8];
        #pragma unroll
        for (int u = 0; u < 8; ++u) v[u] = xp[(size_t)s[u] * 32 + lane];
        #pragma unroll
        for (int u = 0; u < 8; ++u) {
            float m = (i + u < d) ? 1.f : 0.f;
            a[0] += m * bf2f(v[u][0]); a[1] += m * bf2f(v[u][1]);
            a[2] += m * bf2f(v[u][2]); a[3] += m * bf2f(v[u][3]);
        }
    }
    float r = recip[node];
    u16x4 o;
    o[0] = f2bf(a[0] * r); o[1] = f2bf(a[1] * r);
    o[2] = f2bf(a[2] * r); o[3] = f2bf(a[3] * r);
    ((u16x4*)meanb)[(size_t)node * 32 + lane] = o;
}

// ---------------- MFMA SAGE GEMM: out = act([x|mean] @ Bt^T + b) ----------------
// 32 rows x 128 cols per block, 4 waves. A (bf16) staged in LDS XOR-swizzled;
// 4 col-tiles x 8 k-steps of mfma_f32_16x16x32_bf16. Output bf16 (layers 1,2)
// or f32 (layer 3).

template <int RELU, int OUTBF>
__global__ __launch_bounds__(256) void sage_gemm(const ushort* __restrict__ xb,
                                                 const ushort* __restrict__ meanb,
                                                 const ushort* __restrict__ Bt,
                                                 const float* __restrict__ bias,
                                                 void* __restrict__ outp, int N) {
    __shared__ ushort sa[32 * 256];  // 16 KB, [row][k], swizzled
    int tid = threadIdx.x;
    int r0 = blockIdx.x * 32;

    // ---- stage A = [x | mean] (already bf16) ----
    {
        int row = tid >> 3;      // 0..31
        int kc = tid & 7;        // 32-k chunk (64 B)
        int grow = r0 + row;
        const ushort* srcp = (kc < 4) ? &xb[(size_t)grow * 128 + kc * 32]
                                      : &meanb[(size_t)grow * 128 + (kc - 4) * 32];
        uint base = (uint)(row * 512 + kc * 64);
        uint sw = ((uint)row & 7u) << 4;
        #pragma unroll
        for (int c = 0; c < 4; ++c) {
            short8v w;
            if (grow < N) w = ((const short8v*)srcp)[c];
            else          w = (short8v)0;
            *(short8v*)((char*)sa + ((base + c * 16) ^ sw)) = w;
        }
    }
    __syncthreads();

    int lane = tid & 63;
    int wid = tid >> 6;
    int wr = wid & 1;        // row half
    int wc = wid >> 1;       // col quarter (64 cols)
    int l15 = lane & 15;
    int lg = lane >> 4;      // k-group

    // ---- A fragments (8 k-steps) ----
    int arow = wr * 16 + l15;
    uint abase = (uint)(arow * 512 + lg * 16);
    uint asw = ((uint)arow & 7u) << 4;
    bf16x8 a[8];
    #pragma unroll
    for (int ks = 0; ks < 8; ++ks) {
        a[ks] = *(const bf16x8*)((const char*)sa + ((abase + (uint)ks * 64) ^ asw));
    }

    // ---- MFMA: 4 col-tiles x 8 k-steps ----
    f32x4 acc[4];
    #pragma unroll
    for (int ct = 0; ct < 4; ++ct) acc[ct] = (f32x4)0.f;

    #pragma unroll
    for (int ct = 0; ct < 4; ++ct) {
        int bcol = wc * 64 + ct * 16 + l15;
        const ushort* bp = Bt + bcol * 256 + lg * 8;
        #pragma unroll
        for (int ks = 0; ks < 8; ++ks) {
            bf16x8 b = *(const bf16x8*)(bp + ks * 32);
            acc[ct] = __builtin_amdgcn_mfma_f32_16x16x32_bf16(a[ks], b, acc[ct], 0, 0, 0);
        }
    }

    // ---- epilogue: C/D layout col=lane&15, row=(lane>>4)*4+r ----
    int crow = r0 + wr * 16 + lg * 4;
    #pragma unroll
    for (int ct = 0; ct < 4; ++ct) {
        int col = wc * 64 + ct * 16 + l15;
        float bv = bias[col];
        #pragma unroll
        for (int r = 0; r < 4; ++r) {
            int row = crow + r;
            if (row < N) {
                float v = acc[ct][r] + bv;
                if (RELU) v = fmaxf(v, 0.f);
                if (OUTBF) ((ushort*)outp)[(size_t)row * 128 + col] = f2bf(v);
                else       ((float*)outp)[(size_t)row * 128 + col] = v;
            }
        }
    }
}

// ---------------- launch ----------------

extern "C" void kernel_launch(void* const* d_in, const int* in_sizes, int n_in,
                              void* d_out, int out_size, void* d_ws, size_t ws_size,
                              hipStream_t stream) {
    const float* feat = (const float*)d_in[0];
    const int* src = (const int*)d_in[1];
    const int* dst = (const int*)d_in[2];
    const float* W1s = (const float*)d_in[3];
    const float* W1n = (const float*)d_in[4];
    const float* b1 = (const float*)d_in[5];
    const float* W2s = (const float*)d_in[6];
    const float* W2n = (const float*)d_in[7];
    const float* b2 = (const float*)d_in[8];
    const float* W3s = (const float*)d_in[9];
    const float* W3n = (const float*)d_in[10];
    const float* b3 = (const float*)d_in[11];
    float* out = (float*)d_out;

    const int N = NN, E = NE;
    const int NB = (N + 1023) / 1024;  // 49 scan blocks

    char* p = (char*)d_ws;
    auto alloc = [&](size_t bytes) {
        char* q = p;
        p += (bytes + 255) & ~(size_t)255;
        return q;
    };
    int* deg = (int*)alloc((size_t)N * 4);
    int* off = (int*)alloc((size_t)N * 4);
    int* cur = (int*)alloc((size_t)N * 4);
    float* recip = (float*)alloc((size_t)N * 4);
    int* bsum = (int*)alloc(64 * 4);
    int* csr = (int*)alloc((size_t)E * 4);
    ushort* xb0 = (ushort*)alloc((size_t)N * F * 2);
    ushort* h1b = (ushort*)alloc((size_t)N * F * 2);
    ushort* h2b = (ushort*)alloc((size_t)N * F * 2);
    ushort* meanb = (ushort*)alloc((size_t)N * F * 2);
    ushort* Bt1 = (ushort*)alloc(128 * 256 * 2);
    ushort* Bt2 = (ushort*)alloc(128 * 256 * 2);
    ushort* Bt3 = (ushort*)alloc(128 * 256 * 2);

    // weight prep + feature convert (independent of graph prep)
    wt_prep<<<dim3(128, 3), 256, 0, stream>>>(W1s, W1n, W2s, W2n, W3s, W3n, Bt1, Bt2, Bt3);
    to_bf16<<<(N * F / 8 + 255) / 256, 256, 0, stream>>>(feat, xb0, N * F / 8);

    hipMemsetAsync(deg, 0, (size_t)N * 4, stream);
    count_deg<<<(E + 255) / 256, 256, 0, stream>>>(dst, deg, E);
    scan_part1<<<NB, 1024, 0, stream>>>(deg, bsum, N);
    scan_part2<<<1, 64, 0, stream>>>(bsum, NB);
    scan_part3<<<NB, 1024, 0, stream>>>(deg, bsum, off, cur, recip, N);
    fill_csr<<<(E + 255) / 256, 256, 0, stream>>>(src, dst, cur, csr, E);

    int aggGrid = (N + 7) / 8;
    int gemmGrid = (N + 31) / 32;

    // layer 1
    agg_mean<<<aggGrid, 256, 0, stream>>>(xb0, off, deg, recip, csr, meanb, N);
    sage_gemm<1, 1><<<gemmGrid, 256, 0, stream>>>(xb0, meanb, Bt1, b1, h1b, N);
    // layer 2
    agg_mean<<<aggGrid, 256, 0, stream>>>(h1b, off, deg, recip, csr, meanb, N);
    sage_gemm<1, 1><<<gemmGrid, 256, 0, stream>>>(h1b, meanb, Bt2, b2, h2b, N);
    // layer 3 -> f32 d_out
    agg_mean<<<aggGrid, 256, 0, stream>>>(h2b, off, deg, recip, csr, meanb, N);
    sage_gemm<0, 0><<<gemmGrid, 256, 0, stream>>>(h2b, meanb, Bt3, b3, out, N);
}

// Round 8
// 244.373 us; speedup vs baseline: 1.8916x; 1.0370x over previous
//
#include <hip/hip_runtime.h>

#define NN 50000
#define NE 600000
#define F 128

typedef __attribute__((ext_vector_type(4))) float f4;
typedef __attribute__((ext_vector_type(4))) float f32x4;
typedef __bf16 bf16x8 __attribute__((ext_vector_type(8)));
typedef short short8v __attribute__((ext_vector_type(8)));
typedef unsigned short u16x8 __attribute__((ext_vector_type(8)));

__device__ inline ushort f2bf(float f) {
    uint u = __builtin_bit_cast(uint, f);
    uint r = (u + 0x7FFFu + ((u >> 16) & 1u)) >> 16;
    return (ushort)r;
}
__device__ inline float bf2f(ushort u) {
    uint t = ((uint)u) << 16;
    return __builtin_bit_cast(float, t);
}

// ---------------- graph prep ----------------

__global__ void count_deg(const int* __restrict__ dst, int* __restrict__ deg, int E) {
    int e = blockIdx.x * blockDim.x + threadIdx.x;
    if (e < E) atomicAdd(&deg[dst[e]], 1);
}

// pass 1: per-block (1024 elems) sums
__global__ __launch_bounds__(1024) void scan_part1(const int* __restrict__ deg,
                                                   int* __restrict__ bsum, int N) {
    __shared__ int ws[16];
    int tid = threadIdx.x;
    int idx = blockIdx.x * 1024 + tid;
    int v = (idx < N) ? deg[idx] : 0;
    #pragma unroll
    for (int o = 32; o; o >>= 1) v += __shfl_down(v, o);
    if ((tid & 63) == 0) ws[tid >> 6] = v;
    __syncthreads();
    if (tid < 64) {
        int t = (tid < 16) ? ws[tid] : 0;
        #pragma unroll
        for (int o = 8; o; o >>= 1) t += __shfl_down(t, o);
        if (tid == 0) bsum[blockIdx.x] = t;
    }
}

// pass 2+3 fused: every block scans bsum redundantly in wave 0, then local scan
__global__ __launch_bounds__(1024) void scan_part3(const int* __restrict__ deg,
                                                   const int* __restrict__ bsum,
                                                   int* __restrict__ off,
                                                   int* __restrict__ cur,
                                                   float* __restrict__ recip,
                                                   int N, int NB) {
    __shared__ int wsum[16];
    __shared__ int sbase;
    int tid = threadIdx.x;
    int wid = tid >> 6;
    int lane = tid & 63;
    // wave 0: exclusive-scan the block sums, pick this block's base
    if (tid < 64) {
        int v = (tid < NB) ? bsum[tid] : 0;
        int x = v;
        #pragma unroll
        for (int o = 1; o < 64; o <<= 1) {
            int t = __shfl_up(x, o);
            if (lane >= o) x += t;
        }
        if (tid == blockIdx.x) sbase = x - v;
    }
    int idx = blockIdx.x * 1024 + tid;
    int v = (idx < N) ? deg[idx] : 0;
    int x = v;
    #pragma unroll
    for (int o = 1; o < 64; o <<= 1) {
        int t = __shfl_up(x, o);
        if (lane >= o) x += t;
    }
    if (lane == 63) wsum[wid] = x;
    __syncthreads();
    if (tid == 0) {
        int a = 0;
        #pragma unroll
        for (int w = 0; w < 16; ++w) { int t = wsum[w]; wsum[w] = a; a += t; }
    }
    __syncthreads();
    int incl = x + wsum[wid];
    if (idx < N) {
        int start = sbase + incl - v;
        off[idx] = start;
        cur[idx] = start;
        recip[idx] = 1.0f / (float)max(v, 1);
    }
}

__global__ void fill_csr(const int* __restrict__ src, const int* __restrict__ dst,
                         int* __restrict__ cur, int* __restrict__ csr, int E) {
    int e = blockIdx.x * blockDim.x + threadIdx.x;
    if (e < E) {
        int pos = atomicAdd(&cur[dst[e]], 1);
        csr[pos] = src[e];
    }
}

// ---------------- weight prep: Bt[col][k] bf16 for all 3 layers ----------------

__global__ __launch_bounds__(256) void wt_prep(const float* __restrict__ W1s, const float* __restrict__ W1n,
                                               const float* __restrict__ W2s, const float* __restrict__ W2n,
                                               const float* __restrict__ W3s, const float* __restrict__ W3n,
                                               ushort* __restrict__ Bt1, ushort* __restrict__ Bt2,
                                               ushort* __restrict__ Bt3) {
    int layer = blockIdx.y;
    const float* Ws = (layer == 0) ? W1s : (layer == 1) ? W2s : W3s;
    const float* Wn = (layer == 0) ? W1n : (layer == 1) ? W2n : W3n;
    ushort* Bt = (layer == 0) ? Bt1 : (layer == 1) ? Bt2 : Bt3;
    int col = blockIdx.x;
    int k = threadIdx.x;
    float v = (k < 128) ? Ws[k * 128 + col] : Wn[(k - 128) * 128 + col];
    Bt[col * 256 + k] = f2bf(v);
}

// ---------------- f32 -> bf16 feature convert ----------------

__global__ __launch_bounds__(256) void to_bf16(const float* __restrict__ in,
                                               ushort* __restrict__ out, int n8) {
    int i = blockIdx.x * 256 + threadIdx.x;
    if (i < n8) {
        const f4* p = (const f4*)in + (size_t)i * 2;
        f4 a = p[0], b = p[1];
        short8v w;
        w[0] = (short)f2bf(a[0]); w[1] = (short)f2bf(a[1]);
        w[2] = (short)f2bf(a[2]); w[3] = (short)f2bf(a[3]);
        w[4] = (short)f2bf(b[0]); w[5] = (short)f2bf(b[1]);
        w[6] = (short)f2bf(b[2]); w[7] = (short)f2bf(b[3]);
        ((short8v*)out)[i] = w;
    }
}

// ---------------- fused SAGE layer: out = act([x | mean(x,nbrs)] @ Bt^T + b) ----------------
// 32 nodes x 128 cols per block, 256 threads (4 waves). Phase 1: stage x rows
// (k 0..127) into swizzled LDS AND gather-mean neighbors (16 lanes/node, 16B
// u16x8 loads, f32 accumulate) written directly into LDS (k 128..255).
// Phase 2: 4 col-tiles x 8 k-steps of mfma_f32_16x16x32_bf16 per wave.
// Output bf16 (layers 1,2) or f32 (layer 3). No aliasing: out != xb.

template <int RELU, int OUTBF>
__global__ __launch_bounds__(256) void sage_layer(const ushort* __restrict__ xb,
                                                  const int* __restrict__ off,
                                                  const int* __restrict__ deg,
                                                  const float* __restrict__ recip,
                                                  const int* __restrict__ csr,
                                                  const ushort* __restrict__ Bt,
                                                  const float* __restrict__ bias,
                                                  void* __restrict__ outp, int N) {
    __shared__ ushort sa[32 * 256];  // 16 KB, [row][k], XOR-swizzled
    int tid = threadIdx.x;
    int r0 = blockIdx.x * 32;

    // ---- stage x rows (k 0..127): 32B per thread ----
    {
        int row = tid >> 3;      // 0..31
        int c = tid & 7;         // 0..7, 32 B chunks
        int grow = r0 + row;
        uint sw = ((uint)row & 7u) << 4;
        uint base = (uint)(row * 512 + c * 32);
        short8v w0 = (short8v)0, w1 = (short8v)0;
        if (grow < N) {
            const short8v* sp = (const short8v*)&xb[(size_t)grow * 128 + c * 16];
            w0 = sp[0]; w1 = sp[1];
        }
        *(short8v*)((char*)sa + (base ^ sw)) = w0;
        *(short8v*)((char*)sa + ((base + 16) ^ sw)) = w1;
    }

    // ---- gather-mean into LDS (k 128..255): 16 lanes per node ----
    {
        int g = tid >> 4;        // group 0..15
        int l16 = tid & 15;
        const ushort* xpb = xb + (size_t)l16 * 8;  // this lane's 8-col slice
        #pragma unroll
        for (int rep = 0; rep < 2; ++rep) {
            int row = g + rep * 16;
            int node = r0 + row;
            float a[8] = {0.f, 0.f, 0.f, 0.f, 0.f, 0.f, 0.f, 0.f};
            if (node < N) {
                int start = off[node];
                int d = deg[node];
                int nfull = d & ~7;
                int i = 0;
                for (; i < nfull; i += 8) {
                    int s[8];
                    #pragma unroll
                    for (int u = 0; u < 8; ++u) s[u] = csr[start + i + u];
                    u16x8 v[8];
                    #pragma unroll
                    for (int u = 0; u < 8; ++u) v[u] = *(const u16x8*)(xpb + (size_t)s[u] * 128);
                    #pragma unroll
                    for (int u = 0; u < 8; ++u) {
                        #pragma unroll
                        for (int j = 0; j < 8; ++j) a[j] += bf2f(v[u][j]);
                    }
                }
                if (i < d) {
                    int dm1 = d - 1;
                    int s[8];
                    #pragma unroll
                    for (int u = 0; u < 8; ++u) {
                        int idx = i + u;
                        s[u] = csr[start + ((idx < dm1) ? idx : dm1)];
                    }
                    u16x8 v[8];
                    #pragma unroll
                    for (int u = 0; u < 8; ++u) v[u] = *(const u16x8*)(xpb + (size_t)s[u] * 128);
                    #pragma unroll
                    for (int u = 0; u < 8; ++u) {
                        float m = (i + u < d) ? 1.f : 0.f;
                        #pragma unroll
                        for (int j = 0; j < 8; ++j) a[j] += m * bf2f(v[u][j]);
                    }
                }
                float r = recip[node];
                #pragma unroll
                for (int j = 0; j < 8; ++j) a[j] *= r;
            }
            short8v w;
            #pragma unroll
            for (int j = 0; j < 8; ++j) w[j] = (short)f2bf(a[j]);
            uint sw = ((uint)row & 7u) << 4;
            uint addr = (uint)(row * 512 + 256 + l16 * 16);
            *(short8v*)((char*)sa + (addr ^ sw)) = w;
        }
    }
    __syncthreads();

    int lane = tid & 63;
    int wid = tid >> 6;
    int wr = wid & 1;        // row half
    int wc = wid >> 1;       // col quarter (64 cols)
    int l15 = lane & 15;
    int lg = lane >> 4;      // k-group

    // ---- A fragments (8 k-steps) ----
    int arow = wr * 16 + l15;
    uint abase = (uint)(arow * 512 + lg * 16);
    uint asw = ((uint)arow & 7u) << 4;
    bf16x8 a[8];
    #pragma unroll
    for (int ks = 0; ks < 8; ++ks) {
        a[ks] = *(const bf16x8*)((const char*)sa + ((abase + (uint)ks * 64) ^ asw));
    }

    // ---- MFMA: 4 col-tiles x 8 k-steps ----
    f32x4 acc[4];
    #pragma unroll
    for (int ct = 0; ct < 4; ++ct) acc[ct] = (f32x4)0.f;

    #pragma unroll
    for (int ct = 0; ct < 4; ++ct) {
        int bcol = wc * 64 + ct * 16 + l15;
        const ushort* bp = Bt + bcol * 256 + lg * 8;
        #pragma unroll
        for (int ks = 0; ks < 8; ++ks) {
            bf16x8 b = *(const bf16x8*)(bp + ks * 32);
            acc[ct] = __builtin_amdgcn_mfma_f32_16x16x32_bf16(a[ks], b, acc[ct], 0, 0, 0);
        }
    }

    // ---- epilogue: C/D layout col=lane&15, row=(lane>>4)*4+r ----
    int crow = r0 + wr * 16 + lg * 4;
    #pragma unroll
    for (int ct = 0; ct < 4; ++ct) {
        int col = wc * 64 + ct * 16 + l15;
        float bv = bias[col];
        #pragma unroll
        for (int r = 0; r < 4; ++r) {
            int row = crow + r;
            if (row < N) {
                float v = acc[ct][r] + bv;
                if (RELU) v = fmaxf(v, 0.f);
                if (OUTBF) ((ushort*)outp)[(size_t)row * 128 + col] = f2bf(v);
                else       ((float*)outp)[(size_t)row * 128 + col] = v;
            }
        }
    }
}

// ---------------- launch ----------------

extern "C" void kernel_launch(void* const* d_in, const int* in_sizes, int n_in,
                              void* d_out, int out_size, void* d_ws, size_t ws_size,
                              hipStream_t stream) {
    const float* feat = (const float*)d_in[0];
    const int* src = (const int*)d_in[1];
    const int* dst = (const int*)d_in[2];
    const float* W1s = (const float*)d_in[3];
    const float* W1n = (const float*)d_in[4];
    const float* b1 = (const float*)d_in[5];
    const float* W2s = (const float*)d_in[6];
    const float* W2n = (const float*)d_in[7];
    const float* b2 = (const float*)d_in[8];
    const float* W3s = (const float*)d_in[9];
    const float* W3n = (const float*)d_in[10];
    const float* b3 = (const float*)d_in[11];
    float* out = (float*)d_out;

    const int N = NN, E = NE;
    const int NB = (N + 1023) / 1024;  // 49 scan blocks

    char* p = (char*)d_ws;
    auto alloc = [&](size_t bytes) {
        char* q = p;
        p += (bytes + 255) & ~(size_t)255;
        return q;
    };
    int* deg = (int*)alloc((size_t)N * 4);
    int* off = (int*)alloc((size_t)N * 4);
    int* cur = (int*)alloc((size_t)N * 4);
    float* recip = (float*)alloc((size_t)N * 4);
    int* bsum = (int*)alloc(64 * 4);
    int* csr = (int*)alloc((size_t)E * 4);
    ushort* xb0 = (ushort*)alloc((size_t)N * F * 2);
    ushort* h1b = (ushort*)alloc((size_t)N * F * 2);
    ushort* h2b = (ushort*)alloc((size_t)N * F * 2);
    ushort* Bt1 = (ushort*)alloc(128 * 256 * 2);
    ushort* Bt2 = (ushort*)alloc(128 * 256 * 2);
    ushort* Bt3 = (ushort*)alloc(128 * 256 * 2);

    // weight prep + feature convert (independent of graph prep)
    wt_prep<<<dim3(128, 3), 256, 0, stream>>>(W1s, W1n, W2s, W2n, W3s, W3n, Bt1, Bt2, Bt3);
    to_bf16<<<(N * F / 8 + 255) / 256, 256, 0, stream>>>(feat, xb0, N * F / 8);

    hipMemsetAsync(deg, 0, (size_t)N * 4, stream);
    count_deg<<<(E + 255) / 256, 256, 0, stream>>>(dst, deg, E);
    scan_part1<<<NB, 1024, 0, stream>>>(deg, bsum, N);
    scan_part3<<<NB, 1024, 0, stream>>>(deg, bsum, off, cur, recip, N, NB);
    fill_csr<<<(E + 255) / 256, 256, 0, stream>>>(src, dst, cur, csr, E);

    int grid = (N + 31) / 32;

    // layer 1
    sage_layer<1, 1><<<grid, 256, 0, stream>>>(xb0, off, deg, recip, csr, Bt1, b1, h1b, N);
    // layer 2
    sage_layer<1, 1><<<grid, 256, 0, stream>>>(h1b, off, deg, recip, csr, Bt2, b2, h2b, N);
    // layer 3 -> f32 d_out
    sage_layer<0, 0><<<grid, 256, 0, stream>>>(h2b, off, deg, recip, csr, Bt3, b3, out, N);
}

// Round 9
// 244.279 us; speedup vs baseline: 1.8924x; 1.0004x over previous
//
#include <hip/hip_runtime.h>

#define NN 50000
#define NE 600000
#define F 128

typedef __attribute__((ext_vector_type(4))) float f4;
typedef __attribute__((ext_vector_type(4))) float f32x4;
typedef __bf16 bf16x8 __attribute__((ext_vector_type(8)));
typedef short short8v __attribute__((ext_vector_type(8)));
typedef unsigned short u16x8 __attribute__((ext_vector_type(8)));

__device__ inline ushort f2bf(float f) {
    uint u = __builtin_bit_cast(uint, f);
    uint r = (u + 0x7FFFu + ((u >> 16) & 1u)) >> 16;
    return (ushort)r;
}
__device__ inline float bf2f(ushort u) {
    uint t = ((uint)u) << 16;
    return __builtin_bit_cast(float, t);
}

// ---------------- graph prep ----------------

__global__ void count_deg(const int* __restrict__ dst, int* __restrict__ deg, int E) {
    int e = blockIdx.x * blockDim.x + threadIdx.x;
    if (e < E) atomicAdd(&deg[dst[e]], 1);
}

// pass 1: per-block (1024 elems) sums
__global__ __launch_bounds__(1024) void scan_part1(const int* __restrict__ deg,
                                                   int* __restrict__ bsum, int N) {
    __shared__ int ws[16];
    int tid = threadIdx.x;
    int idx = blockIdx.x * 1024 + tid;
    int v = (idx < N) ? deg[idx] : 0;
    #pragma unroll
    for (int o = 32; o; o >>= 1) v += __shfl_down(v, o);
    if ((tid & 63) == 0) ws[tid >> 6] = v;
    __syncthreads();
    if (tid < 64) {
        int t = (tid < 16) ? ws[tid] : 0;
        #pragma unroll
        for (int o = 8; o; o >>= 1) t += __shfl_down(t, o);
        if (tid == 0) bsum[blockIdx.x] = t;
    }
}

// pass 2+3 fused: every block scans bsum redundantly in wave 0, then local scan
__global__ __launch_bounds__(1024) void scan_part3(const int* __restrict__ deg,
                                                   const int* __restrict__ bsum,
                                                   int* __restrict__ off,
                                                   int* __restrict__ cur,
                                                   float* __restrict__ recip,
                                                   int N, int NB) {
    __shared__ int wsum[16];
    __shared__ int sbase;
    int tid = threadIdx.x;
    int wid = tid >> 6;
    int lane = tid & 63;
    // wave 0: exclusive-scan the block sums, pick this block's base
    if (tid < 64) {
        int v = (tid < NB) ? bsum[tid] : 0;
        int x = v;
        #pragma unroll
        for (int o = 1; o < 64; o <<= 1) {
            int t = __shfl_up(x, o);
            if (lane >= o) x += t;
        }
        if (tid == blockIdx.x) sbase = x - v;
    }
    int idx = blockIdx.x * 1024 + tid;
    int v = (idx < N) ? deg[idx] : 0;
    int x = v;
    #pragma unroll
    for (int o = 1; o < 64; o <<= 1) {
        int t = __shfl_up(x, o);
        if (lane >= o) x += t;
    }
    if (lane == 63) wsum[wid] = x;
    __syncthreads();
    if (tid == 0) {
        int a = 0;
        #pragma unroll
        for (int w = 0; w < 16; ++w) { int t = wsum[w]; wsum[w] = a; a += t; }
    }
    __syncthreads();
    int incl = x + wsum[wid];
    if (idx < N) {
        int start = sbase + incl - v;
        off[idx] = start;
        cur[idx] = start;
        recip[idx] = 1.0f / (float)max(v, 1);
    }
}

__global__ void fill_csr(const int* __restrict__ src, const int* __restrict__ dst,
                         int* __restrict__ cur, int* __restrict__ csr, int E) {
    int e = blockIdx.x * blockDim.x + threadIdx.x;
    if (e < E) {
        int pos = atomicAdd(&cur[dst[e]], 1);
        csr[pos] = src[e];
    }
}

// ---------------- weight prep: Bt[col][k] bf16 for all 3 layers ----------------

__global__ __launch_bounds__(256) void wt_prep(const float* __restrict__ W1s, const float* __restrict__ W1n,
                                               const float* __restrict__ W2s, const float* __restrict__ W2n,
                                               const float* __restrict__ W3s, const float* __restrict__ W3n,
                                               ushort* __restrict__ Bt1, ushort* __restrict__ Bt2,
                                               ushort* __restrict__ Bt3) {
    int layer = blockIdx.y;
    const float* Ws = (layer == 0) ? W1s : (layer == 1) ? W2s : W3s;
    const float* Wn = (layer == 0) ? W1n : (layer == 1) ? W2n : W3n;
    ushort* Bt = (layer == 0) ? Bt1 : (layer == 1) ? Bt2 : Bt3;
    int col = blockIdx.x;
    int k = threadIdx.x;
    float v = (k < 128) ? Ws[k * 128 + col] : Wn[(k - 128) * 128 + col];
    Bt[col * 256 + k] = f2bf(v);
}

// ---------------- f32 -> bf16 feature convert ----------------

__global__ __launch_bounds__(256) void to_bf16(const float* __restrict__ in,
                                               ushort* __restrict__ out, int n8) {
    int i = blockIdx.x * 256 + threadIdx.x;
    if (i < n8) {
        const f4* p = (const f4*)in + (size_t)i * 2;
        f4 a = p[0], b = p[1];
        short8v w;
        w[0] = (short)f2bf(a[0]); w[1] = (short)f2bf(a[1]);
        w[2] = (short)f2bf(a[2]); w[3] = (short)f2bf(a[3]);
        w[4] = (short)f2bf(b[0]); w[5] = (short)f2bf(b[1]);
        w[6] = (short)f2bf(b[2]); w[7] = (short)f2bf(b[3]);
        ((short8v*)out)[i] = w;
    }
}

// ---------------- fused SAGE layer: out = act([x | mean(x,nbrs)] @ Bt^T + b) ----------------
// 32 nodes x 128 cols per block, 256 threads (4 waves). Phase 1: stage x rows
// (k 0..127) into swizzled LDS AND gather-mean neighbors (16 lanes/node, 16B
// u16x8 loads, f32 accumulate) written directly into LDS (k 128..255).
// Phase 2: 4 col-tiles x 8 k-steps of mfma_f32_16x16x32_bf16 per wave.
// Output bf16 (layers 1,2) or f32 (layer 3). No aliasing: out != xb.

template <int RELU, int OUTBF>
__global__ __launch_bounds__(256) void sage_layer(const ushort* __restrict__ xb,
                                                  const int* __restrict__ off,
                                                  const int* __restrict__ deg,
                                                  const float* __restrict__ recip,
                                                  const int* __restrict__ csr,
                                                  const ushort* __restrict__ Bt,
                                                  const float* __restrict__ bias,
                                                  void* __restrict__ outp, int N) {
    __shared__ ushort sa[32 * 256];  // 16 KB, [row][k], XOR-swizzled
    int tid = threadIdx.x;
    int r0 = blockIdx.x * 32;

    // ---- stage x rows (k 0..127): 32B per thread ----
    {
        int row = tid >> 3;      // 0..31
        int c = tid & 7;         // 0..7, 32 B chunks
        int grow = r0 + row;
        uint sw = ((uint)row & 7u) << 4;
        uint base = (uint)(row * 512 + c * 32);
        short8v w0 = (short8v)0, w1 = (short8v)0;
        if (grow < N) {
            const short8v* sp = (const short8v*)&xb[(size_t)grow * 128 + c * 16];
            w0 = sp[0]; w1 = sp[1];
        }
        *(short8v*)((char*)sa + (base ^ sw)) = w0;
        *(short8v*)((char*)sa + ((base + 16) ^ sw)) = w1;
    }

    // ---- gather-mean into LDS (k 128..255): 16 lanes per node ----
    {
        int g = tid >> 4;        // group 0..15
        int l16 = tid & 15;
        const ushort* xpb = xb + (size_t)l16 * 8;  // this lane's 8-col slice
        #pragma unroll
        for (int rep = 0; rep < 2; ++rep) {
            int row = g + rep * 16;
            int node = r0 + row;
            float a[8] = {0.f, 0.f, 0.f, 0.f, 0.f, 0.f, 0.f, 0.f};
            if (node < N) {
                int start = off[node];
                int d = deg[node];
                int nfull = d & ~7;
                int i = 0;
                for (; i < nfull; i += 8) {
                    int s[8];
                    #pragma unroll
                    for (int u = 0; u < 8; ++u) s[u] = csr[start + i + u];
                    u16x8 v[8];
                    #pragma unroll
                    for (int u = 0; u < 8; ++u) v[u] = *(const u16x8*)(xpb + (size_t)s[u] * 128);
                    #pragma unroll
                    for (int u = 0; u < 8; ++u) {
                        #pragma unroll
                        for (int j = 0; j < 8; ++j) a[j] += bf2f(v[u][j]);
                    }
                }
                if (i < d) {
                    int dm1 = d - 1;
                    int s[8];
                    #pragma unroll
                    for (int u = 0; u < 8; ++u) {
                        int idx = i + u;
                        s[u] = csr[start + ((idx < dm1) ? idx : dm1)];
                    }
                    u16x8 v[8];
                    #pragma unroll
                    for (int u = 0; u < 8; ++u) v[u] = *(const u16x8*)(xpb + (size_t)s[u] * 128);
                    #pragma unroll
                    for (int u = 0; u < 8; ++u) {
                        float m = (i + u < d) ? 1.f : 0.f;
                        #pragma unroll
                        for (int j = 0; j < 8; ++j) a[j] += m * bf2f(v[u][j]);
                    }
                }
                float r = recip[node];
                #pragma unroll
                for (int j = 0; j < 8; ++j) a[j] *= r;
            }
            short8v w;
            #pragma unroll
            for (int j = 0; j < 8; ++j) w[j] = (short)f2bf(a[j]);
            uint sw = ((uint)row & 7u) << 4;
            uint addr = (uint)(row * 512 + 256 + l16 * 16);
            *(short8v*)((char*)sa + (addr ^ sw)) = w;
        }
    }
    __syncthreads();

    int lane = tid & 63;
    int wid = tid >> 6;
    int wr = wid & 1;        // row half
    int wc = wid >> 1;       // col quarter (64 cols)
    int l15 = lane & 15;
    int lg = lane >> 4;      // k-group

    // ---- A fragments (8 k-steps) ----
    int arow = wr * 16 + l15;
    uint abase = (uint)(arow * 512 + lg * 16);
    uint asw = ((uint)arow & 7u) << 4;
    bf16x8 a[8];
    #pragma unroll
    for (int ks = 0; ks < 8; ++ks) {
        a[ks] = *(const bf16x8*)((const char*)sa + ((abase + (uint)ks * 64) ^ asw));
    }

    // ---- MFMA: 4 col-tiles x 8 k-steps ----
    f32x4 acc[4];
    #pragma unroll
    for (int ct = 0; ct < 4; ++ct) acc[ct] = (f32x4)0.f;

    #pragma unroll
    for (int ct = 0; ct < 4; ++ct) {
        int bcol = wc * 64 + ct * 16 + l15;
        const ushort* bp = Bt + bcol * 256 + lg * 8;
        #pragma unroll
        for (int ks = 0; ks < 8; ++ks) {
            bf16x8 b = *(const bf16x8*)(bp + ks * 32);
            acc[ct] = __builtin_amdgcn_mfma_f32_16x16x32_bf16(a[ks], b, acc[ct], 0, 0, 0);
        }
    }

    // ---- epilogue: C/D layout col=lane&15, row=(lane>>4)*4+r ----
    int crow = r0 + wr * 16 + lg * 4;
    #pragma unroll
    for (int ct = 0; ct < 4; ++ct) {
        int col = wc * 64 + ct * 16 + l15;
        float bv = bias[col];
        #pragma unroll
        for (int r = 0; r < 4; ++r) {
            int row = crow + r;
            if (row < N) {
                float v = acc[ct][r] + bv;
                if (RELU) v = fmaxf(v, 0.f);
                if (OUTBF) ((ushort*)outp)[(size_t)row * 128 + col] = f2bf(v);
                else       ((float*)outp)[(size_t)row * 128 + col] = v;
            }
        }
    }
}

// ---------------- launch ----------------

extern "C" void kernel_launch(void* const* d_in, const int* in_sizes, int n_in,
                              void* d_out, int out_size, void* d_ws, size_t ws_size,
                              hipStream_t stream) {
    const float* feat = (const float*)d_in[0];
    const int* src = (const int*)d_in[1];
    const int* dst = (const int*)d_in[2];
    const float* W1s = (const float*)d_in[3];
    const float* W1n = (const float*)d_in[4];
    const float* b1 = (const float*)d_in[5];
    const float* W2s = (const float*)d_in[6];
    const float* W2n = (const float*)d_in[7];
    const float* b2 = (const float*)d_in[8];
    const float* W3s = (const float*)d_in[9];
    const float* W3n = (const float*)d_in[10];
    const float* b3 = (const float*)d_in[11];
    float* out = (float*)d_out;

    const int N = NN, E = NE;
    const int NB = (N + 1023) / 1024;  // 49 scan blocks

    char* p = (char*)d_ws;
    auto alloc = [&](size_t bytes) {
        char* q = p;
        p += (bytes + 255) & ~(size_t)255;
        return q;
    };
    int* deg = (int*)alloc((size_t)N * 4);
    int* off = (int*)alloc((size_t)N * 4);
    int* cur = (int*)alloc((size_t)N * 4);
    float* recip = (float*)alloc((size_t)N * 4);
    int* bsum = (int*)alloc(64 * 4);
    int* csr = (int*)alloc((size_t)E * 4);
    ushort* xb0 = (ushort*)alloc((size_t)N * F * 2);
    ushort* h1b = (ushort*)alloc((size_t)N * F * 2);
    ushort* h2b = (ushort*)alloc((size_t)N * F * 2);
    ushort* Bt1 = (ushort*)alloc(128 * 256 * 2);
    ushort* Bt2 = (ushort*)alloc(128 * 256 * 2);
    ushort* Bt3 = (ushort*)alloc(128 * 256 * 2);

    // weight prep + feature convert (independent of graph prep)
    wt_prep<<<dim3(128, 3), 256, 0, stream>>>(W1s, W1n, W2s, W2n, W3s, W3n, Bt1, Bt2, Bt3);
    to_bf16<<<(N * F / 8 + 255) / 256, 256, 0, stream>>>(feat, xb0, N * F / 8);

    hipMemsetAsync(deg, 0, (size_t)N * 4, stream);
    count_deg<<<(E + 255) / 256, 256, 0, stream>>>(dst, deg, E);
    scan_part1<<<NB, 1024, 0, stream>>>(deg, bsum, N);
    scan_part3<<<NB, 1024, 0, stream>>>(deg, bsum, off, cur, recip, N, NB);
    fill_csr<<<(E + 255) / 256, 256, 0, stream>>>(src, dst, cur, csr, E);

    int grid = (N + 31) / 32;

    // layer 1
    sage_layer<1, 1><<<grid, 256, 0, stream>>>(xb0, off, deg, recip, csr, Bt1, b1, h1b, N);
    // layer 2
    sage_layer<1, 1><<<grid, 256, 0, stream>>>(h1b, off, deg, recip, csr, Bt2, b2, h2b, N);
    // layer 3 -> f32 d_out
    sage_layer<0, 0><<<grid, 256, 0, stream>>>(h2b, off, deg, recip, csr, Bt3, b3, out, N);
}